// Round 2
// baseline (46.073 us; speedup 1.0000x reference)
//
#include <hip/hip_runtime.h>

#define B_ 4096
#define C_ 64
#define F_ 128
#define XLD 132  // padded row stride (floats) for the x tile: breaks 4-way bank aliasing

// ---------------------------------------------------------------------------
// Kernel A: e_bar[b][f] = (1/C) * sum_c emb[b][c][f]
// One block per batch. 256 threads, float4 coalesced streaming. ~20us (HBM).
// ---------------------------------------------------------------------------
__global__ __launch_bounds__(256) void mean_kernel(const float* __restrict__ emb,
                                                   float* __restrict__ ebar) {
    const int b = blockIdx.x;
    const int t = threadIdx.x;
    const int fc = t & 31;   // float4 column index (32 per row)
    const int cr = t >> 5;   // row group 0..7

    const float4* src = (const float4*)(emb + (size_t)b * C_ * F_);
    float4 s = make_float4(0.f, 0.f, 0.f, 0.f);
    #pragma unroll
    for (int c = 0; c < C_ / 8; ++c) {
        float4 v = src[(cr + c * 8) * (F_ / 4) + fc];
        s.x += v.x; s.y += v.y; s.z += v.z; s.w += v.w;
    }

    __shared__ float4 part[8][32];
    part[cr][fc] = s;
    __syncthreads();
    if (t < 32) {
        float4 acc = part[0][t];
        #pragma unroll
        for (int i = 1; i < 8; ++i) {
            float4 v = part[i][t];
            acc.x += v.x; acc.y += v.y; acc.z += v.z; acc.w += v.w;
        }
        const float inv = 1.0f / (float)C_;
        acc.x *= inv; acc.y *= inv; acc.z *= inv; acc.w *= inv;
        ((float4*)(ebar + (size_t)b * F_))[t] = acc;
    }
}

// ---------------------------------------------------------------------------
// Async 64KB weight stage: global -> LDS, width-16 global_load_lds.
// 128 threads = 2 waves; wave w stages bytes [w*32KB, (w+1)*32KB).
// Dest is lane-linear (base + lane*16) as the HW requires.
// ---------------------------------------------------------------------------
typedef __attribute__((address_space(3))) unsigned int  lds_u32;
typedef __attribute__((address_space(1))) unsigned int  glb_u32;

__device__ __forceinline__ void stage_w(const float* __restrict__ Wg,
                                        float* buf, int t) {
    const int wv = t >> 6;     // wave id 0..1
    const int ln = t & 63;     // lane
    #pragma unroll
    for (int c = 0; c < 32; ++c) {
        const int off = wv * 8192 + c * 256 + ln * 4;   // float index, 16B per lane
        __builtin_amdgcn_global_load_lds((const glb_u32*)(Wg + off),
                                         (lds_u32*)(buf + off), 16, 0, 0);
    }
}

// ---------------------------------------------------------------------------
// Kernel B: fused 4-layer MLP on [4096,128] rows.
// 256 blocks x 128 threads (2 waves), 16 rows/block.
// Thread (cg = t&31, Q = t>>5): rows Q*4..Q*4+3, cols 4cg..4cg+3 (4x4 blocking).
// Per k4: 4 x-broadcast b128 + 4 W-row b128 feed 64 FMAs -> VALU/ds balanced.
// W double-buffered in LDS, staged async for layer l+1 during layer l.
// x rows are wave-disjoint: wave0 owns rows 0..7, wave1 rows 8..15 -> the one
// __syncthreads() per layer (drains vmcnt for the W stage) covers everything.
// ---------------------------------------------------------------------------
__global__ __launch_bounds__(128) void mlp_kernel(const float* __restrict__ xin,
                                                  const float* __restrict__ W0,
                                                  const float* __restrict__ b0,
                                                  const float* __restrict__ W1,
                                                  const float* __restrict__ b1,
                                                  const float* __restrict__ W2,
                                                  const float* __restrict__ b2,
                                                  const float* __restrict__ Wr,
                                                  const float* __restrict__ br,
                                                  float* __restrict__ out) {
    __shared__ float Wbuf[2][F_ * F_];   // 2 x 64KB
    __shared__ float xb[16 * XLD];       // 8.25KB  (total ~136.5KB LDS)

    const int t  = threadIdx.x;
    const int cg = t & 31;               // float4 col group
    const int Q  = t >> 5;               // row quad 0..3 -> rows Q*4..Q*4+3
    const int row0 = blockIdx.x * 16;

    // load x tile (16 rows x 128) into padded LDS: 512 float4, 4 per thread
    {
        const float4* src = (const float4*)(xin + (size_t)row0 * F_);
        #pragma unroll
        for (int i = 0; i < 4; ++i) {
            const int idx = t + i * 128;        // float4 slot
            const int r = idx >> 5, c4 = idx & 31;
            *(float4*)(xb + r * XLD + c4 * 4) = src[idx];
        }
    }

    const float* Ws[4] = {W0, W1, W2, Wr};
    const float* bs[4] = {b0, b1, b2, br};

    stage_w(Ws[0], Wbuf[0], t);
    __syncthreads();                     // W0 staged (vmcnt drained) + x visible

    #pragma unroll
    for (int l = 0; l < 4; ++l) {
        if (l < 3) stage_w(Ws[l + 1], Wbuf[(l + 1) & 1], t);   // async prefetch
        const float* Wl = Wbuf[l & 1];
        const float4 bias = ((const float4*)bs[l])[cg];

        float4 acc[4];
        #pragma unroll
        for (int j = 0; j < 4; ++j) acc[j] = make_float4(0.f, 0.f, 0.f, 0.f);

        #pragma unroll 4
        for (int k4 = 0; k4 < 32; ++k4) {
            float4 xv[4];
            #pragma unroll
            for (int j = 0; j < 4; ++j)
                xv[j] = *(const float4*)(xb + (Q * 4 + j) * XLD + k4 * 4);
            #pragma unroll
            for (int i = 0; i < 4; ++i) {
                const float4 w = *(const float4*)(Wl + (k4 * 4 + i) * F_ + cg * 4);
                #pragma unroll
                for (int j = 0; j < 4; ++j) {
                    const float xs = (&xv[j].x)[i];   // static after unroll
                    acc[j].x += xs * w.x; acc[j].y += xs * w.y;
                    acc[j].z += xs * w.z; acc[j].w += xs * w.w;
                }
            }
        }

        if (l < 3) {
            #pragma unroll
            for (int j = 0; j < 4; ++j) {
                float4 r;
                r.x = fmaxf(acc[j].x + bias.x, 0.f);
                r.y = fmaxf(acc[j].y + bias.y, 0.f);
                r.z = fmaxf(acc[j].z + bias.z, 0.f);
                r.w = fmaxf(acc[j].w + bias.w, 0.f);
                *(float4*)(xb + (Q * 4 + j) * XLD + cg * 4) = r;
            }
            __syncthreads();   // x' cross-lane visible; W_{l+1} stage drained
        } else {
            float4* o = (float4*)(out + (size_t)row0 * F_);
            #pragma unroll
            for (int j = 0; j < 4; ++j) {
                float4 r;
                r.x = acc[j].x + bias.x; r.y = acc[j].y + bias.y;
                r.z = acc[j].z + bias.z; r.w = acc[j].w + bias.w;
                o[(Q * 4 + j) * 32 + cg] = r;
            }
        }
    }
}

extern "C" void kernel_launch(void* const* d_in, const int* in_sizes, int n_in,
                              void* d_out, int out_size, void* d_ws, size_t ws_size,
                              hipStream_t stream) {
    const float* emb = (const float*)d_in[0];
    const float* W0  = (const float*)d_in[1];
    const float* b0  = (const float*)d_in[2];
    const float* W1  = (const float*)d_in[3];
    const float* b1  = (const float*)d_in[4];
    const float* W2  = (const float*)d_in[5];
    const float* b2  = (const float*)d_in[6];
    const float* Wr  = (const float*)d_in[7];
    const float* br  = (const float*)d_in[8];

    float* ebar = (float*)d_ws;  // 4096*128*4 = 2 MB scratch

    mean_kernel<<<B_, 256, 0, stream>>>(emb, ebar);
    mlp_kernel<<<B_ / 16, 128, 0, stream>>>(ebar, W0, b0, W1, b1, W2, b2,
                                            Wr, br, (float*)d_out);
}

// Round 4
// 43.343 us; speedup vs baseline: 1.0630x; 1.0630x over previous
//
#include <hip/hip_runtime.h>

#define B_   4096
#define C_   64
#define F_   128
#define XLD  132   // padded x row stride (floats); 132%4==0 keeps float4 alignment
#define ROWS 16    // batches per block

typedef __attribute__((address_space(3))) unsigned int lds_u32;
typedef __attribute__((address_space(1))) unsigned int glb_u32;

// Async 64KB weight stage global->LDS, width-16, lane-linear dest.
// Wave w, lane ln: base = i*4096 + 1024*w bytes, + ln*16  (HW-required layout).
__device__ __forceinline__ void stage_w(const float* __restrict__ Wg,
                                        float* buf, int t) {
    #pragma unroll
    for (int i = 0; i < 16; ++i) {
        const int off = i * 1024 + t * 4;   // float index
        __builtin_amdgcn_global_load_lds((const glb_u32*)(Wg + off),
                                         (lds_u32*)(buf + off), 16, 0, 0);
    }
}

// ---------------------------------------------------------------------------
// Fused: phase 1 streams the per-batch mean (16 batches/block) into LDS,
// phase 2 runs the 4-layer MLP with 2-way k-split:
//   wave-pair p (threads 128p..128p+127) computes partial sums over
//   k in [64p, 64p+64); thread (rg = tp>>5, cf = tp&31) owns rows rg*4..rg*4+3
//   x cols [4cf,4cf+4). Partials go to Pbuf[p]; a distributed reduce adds
//   them, applies bias(+relu), and writes xb (or out for the last layer).
// W double-buffered + staged async; every __syncthreads() drains vmcnt.
// ---------------------------------------------------------------------------
__global__ __launch_bounds__(256, 1) void fused_kernel(const float* __restrict__ emb,
                                                       const float* __restrict__ W0,
                                                       const float* __restrict__ b0,
                                                       const float* __restrict__ W1,
                                                       const float* __restrict__ b1,
                                                       const float* __restrict__ W2,
                                                       const float* __restrict__ b2,
                                                       const float* __restrict__ Wr,
                                                       const float* __restrict__ br,
                                                       float* __restrict__ out) {
    __shared__ float Wbuf[2][F_ * F_];     // 128 KB
    __shared__ float xb[ROWS * XLD];       // 8.25 KB
    __shared__ float Pbuf[2][ROWS * F_];   // 16 KB   (total 152.25 KB)

    const int t    = threadIdx.x;
    const int row0 = blockIdx.x * ROWS;

    // W0 prefetch rides under the streaming phase.
    stage_w(W0, Wbuf[0], t);

    // per-thread bias float4s (col group = t&31, same for both reduce slots)
    float4 bias4[4];
    bias4[0] = ((const float4*)b0)[t & 31];
    bias4[1] = ((const float4*)b1)[t & 31];
    bias4[2] = ((const float4*)b2)[t & 31];
    bias4[3] = ((const float4*)br)[t & 31];

    // ---------------- Phase 1: mean over C=64, 2 batches per thread --------
    {
        const int fc = t & 31;   // float4 column
        const int bb = t >> 5;   // batches 2bb, 2bb+1
        const float4* s0 = (const float4*)(emb + (size_t)(row0 + 2 * bb) * C_ * F_);
        const float4* s1 = s0 + C_ * F_ / 4;
        float4 a0 = make_float4(0.f, 0.f, 0.f, 0.f);
        float4 a1 = make_float4(0.f, 0.f, 0.f, 0.f);
        #pragma unroll 8
        for (int c = 0; c < C_; ++c) {
            float4 v0 = s0[c * 32 + fc];
            float4 v1 = s1[c * 32 + fc];
            a0.x += v0.x; a0.y += v0.y; a0.z += v0.z; a0.w += v0.w;
            a1.x += v1.x; a1.y += v1.y; a1.z += v1.z; a1.w += v1.w;
        }
        const float inv = 1.0f / (float)C_;
        a0.x *= inv; a0.y *= inv; a0.z *= inv; a0.w *= inv;
        a1.x *= inv; a1.y *= inv; a1.z *= inv; a1.w *= inv;
        *(float4*)(xb + (2 * bb)     * XLD + fc * 4) = a0;
        *(float4*)(xb + (2 * bb + 1) * XLD + fc * 4) = a1;
    }
    __syncthreads();   // xb visible; W0 staged (vmcnt drained at barrier)

    // ---------------- Phase 2: 4-layer MLP, 2-way k-split -------------------
    const float* Ws[4] = {W0, W1, W2, Wr};

    const int tp   = t & 127;
    const int pair = t >> 7;          // k in [64*pair, 64*pair+64)
    const int rg   = tp >> 5;         // rows rg*4 .. rg*4+3
    const int cf   = tp & 31;         // float4 col
    const int k4lo = pair * 16;       // k-quad range [k4lo, k4lo+16)

    #pragma unroll
    for (int l = 0; l < 4; ++l) {
        if (l < 3) stage_w(Ws[l + 1], Wbuf[(l + 1) & 1], t);   // async prefetch
        const float* Wl = Wbuf[l & 1];

        float4 acc[4];
        #pragma unroll
        for (int j = 0; j < 4; ++j) acc[j] = make_float4(0.f, 0.f, 0.f, 0.f);

        #pragma unroll 4
        for (int kq = 0; kq < 16; ++kq) {
            const int k4 = k4lo + kq;
            float4 xv[4];
            #pragma unroll
            for (int j = 0; j < 4; ++j)
                xv[j] = *(const float4*)(xb + (rg * 4 + j) * XLD + k4 * 4);
            #pragma unroll
            for (int i = 0; i < 4; ++i) {
                const float4 w = *(const float4*)(Wl + (k4 * 4 + i) * F_ + cf * 4);
                #pragma unroll
                for (int j = 0; j < 4; ++j) {
                    const float xs = (&xv[j].x)[i];   // static after full unroll
                    acc[j].x += xs * w.x; acc[j].y += xs * w.y;
                    acc[j].z += xs * w.z; acc[j].w += xs * w.w;
                }
            }
        }

        // write partial tile
        #pragma unroll
        for (int j = 0; j < 4; ++j)
            *(float4*)(&Pbuf[pair][(rg * 4 + j) * F_ + cf * 4]) = acc[j];
        __syncthreads();   // partials complete

        // distributed reduce: thread handles float4 slots {t, t+256} (cf = t&31)
        if (l < 3) {
            #pragma unroll
            for (int q = 0; q < 2; ++q) {
                const int s   = t + q * 256;
                const int row = s >> 5, c4 = s & 31;
                const float4 p0 = *(const float4*)(&Pbuf[0][row * F_ + c4 * 4]);
                const float4 p1 = *(const float4*)(&Pbuf[1][row * F_ + c4 * 4]);
                float4 r;
                r.x = fmaxf(p0.x + p1.x + bias4[l].x, 0.f);
                r.y = fmaxf(p0.y + p1.y + bias4[l].y, 0.f);
                r.z = fmaxf(p0.z + p1.z + bias4[l].z, 0.f);
                r.w = fmaxf(p0.w + p1.w + bias4[l].w, 0.f);
                *(float4*)(xb + row * XLD + c4 * 4) = r;
            }
            __syncthreads();   // xb' visible; next W staged; P reads done
        } else {
            float4* o = (float4*)(out + (size_t)row0 * F_);
            #pragma unroll
            for (int q = 0; q < 2; ++q) {
                const int s   = t + q * 256;
                const int row = s >> 5, c4 = s & 31;
                const float4 p0 = *(const float4*)(&Pbuf[0][row * F_ + c4 * 4]);
                const float4 p1 = *(const float4*)(&Pbuf[1][row * F_ + c4 * 4]);
                float4 r;
                r.x = p0.x + p1.x + bias4[3].x;
                r.y = p0.y + p1.y + bias4[3].y;
                r.z = p0.z + p1.z + bias4[3].z;
                r.w = p0.w + p1.w + bias4[3].w;
                o[s] = r;
            }
        }
    }
}

extern "C" void kernel_launch(void* const* d_in, const int* in_sizes, int n_in,
                              void* d_out, int out_size, void* d_ws, size_t ws_size,
                              hipStream_t stream) {
    const float* emb = (const float*)d_in[0];
    const float* W0  = (const float*)d_in[1];
    const float* b0  = (const float*)d_in[2];
    const float* W1  = (const float*)d_in[3];
    const float* b1  = (const float*)d_in[4];
    const float* W2  = (const float*)d_in[5];
    const float* b2  = (const float*)d_in[6];
    const float* Wr  = (const float*)d_in[7];
    const float* br  = (const float*)d_in[8];

    fused_kernel<<<B_ / ROWS, 256, 0, stream>>>(emb, W0, b0, W1, b1, W2, b2,
                                                Wr, br, (float*)d_out);
}